// Round 1
// baseline (2417.239 us; speedup 1.0000x reference)
//
#include <hip/hip_runtime.h>
#include <stdint.h>

#define Vn 10242
#define Ln 42
#define LPn 48
#define VPn 10496   /* 41*256 padded rows */
#define RBn 41
#define NITER 5

typedef float4 f4;

// ---------------- init flags + c value ----------------
__global__ void k_init0(int* flags, const float* __restrict__ F) {
    if (threadIdx.x == 0 && blockIdx.x == 0) {
        flags[0] = 0;                       // F non-uniform violation
        flags[1] = 0;                       // S non-diagonal violation
        ((float*)flags)[2] = F[0];          // candidate uniform value c
    }
}

// ---------------- structure detection: F uniform? S diagonal? extract diag(S) ----------------
__global__ __launch_bounds__(256) void k_detect(const float* __restrict__ F,
                                                const float* __restrict__ S,
                                                int* flags, float* __restrict__ diagS) {
    int j = blockIdx.x * 256 + threadIdx.x;
    if (j >= Vn) return;
    const float c0 = F[0];
    int violF = 0, violS = 0;
    for (int i = blockIdx.y; i < Vn; i += (int)gridDim.y) {
        size_t idx = (size_t)i * Vn + j;
        float f = F[idx];
        float s = S[idx];
        violF |= (f != c0);
        if (i == j) diagS[j] = s;
        else violS |= (s != 0.0f);
    }
    if (violF) atomicOr(&flags[0], 1);
    if (violS) atomicOr(&flags[1], 1);
}

// ---------------- U = log(clip(def_idxs)), q0 = softmax(U), pack coords ----------------
__global__ __launch_bounds__(256) void k_initU(const float* __restrict__ didx,
                                               const float* __restrict__ coords,
                                               float* __restrict__ U, float* __restrict__ q,
                                               float* __restrict__ xyz) {
    int row = blockIdx.x * 256 + threadIdx.x;
    if (row >= Vn) return;
    xyz[(size_t)row * 4 + 0] = coords[(size_t)row * 3 + 0];
    xyz[(size_t)row * 4 + 1] = coords[(size_t)row * 3 + 1];
    xyz[(size_t)row * 4 + 2] = coords[(size_t)row * 3 + 2];
    xyz[(size_t)row * 4 + 3] = 0.0f;
    float u[Ln];
    float mx = -3.0e38f;
    #pragma unroll
    for (int l = 0; l < Ln; ++l) {
        float x = didx[(size_t)row * Ln + l];
        x = fminf(fmaxf(x, 1e-6f), 1.0f);
        u[l] = __logf(x);
        mx = fmaxf(mx, u[l]);
    }
    float s = 0.0f;
    float e[Ln];
    #pragma unroll
    for (int l = 0; l < Ln; ++l) { e[l] = __expf(u[l] - mx); s += e[l]; }
    float inv = 1.0f / s;
    #pragma unroll
    for (int l = 0; l < Ln; ++l) {
        U[(size_t)row * LPn + l] = u[l];
        q[(size_t)row * LPn + l] = e[l] * inv;
    }
    #pragma unroll
    for (int l = Ln; l < LPn; ++l) {
        U[(size_t)row * LPn + l] = 0.0f;
        q[(size_t)row * LPn + l] = 0.0f;   // zero pad: contributes 0 to FMAs
    }
}

// ---------------- fast path: phi_t partials = G @ q  (F uniform; c applied later) ----------------
__global__ __launch_bounds__(256) void k_phi_fast(const float* __restrict__ q,
                                                  const float* __restrict__ xyz,
                                                  float* __restrict__ part,
                                                  const int* __restrict__ flags, int jchunk) {
    if (flags[0]) return;   // F not uniform -> general kernel owns this iteration
    int row = blockIdx.x * 256 + threadIdx.x;
    if (row >= Vn) return;
    int j0 = blockIdx.y * jchunk;
    int j1 = j0 + jchunk; if (j1 > Vn) j1 = Vn;
    f4 xi = *(const f4*)(xyz + (size_t)row * 4);
    f4 acc[12];
    #pragma unroll
    for (int c = 0; c < 12; ++c) acc[c] = make_float4(0.f, 0.f, 0.f, 0.f);
    for (int j = j0; j < j1; ++j) {
        f4 xj = *(const f4*)(xyz + (size_t)j * 4);
        float dx = xi.x - xj.x, dy = xi.y - xj.y, dz = xi.z - xj.z;
        float d2 = dx * dx + dy * dy + dz * dz;
        float w = __expf(-2.0f * d2);
        w = (j == row) ? 0.0f : w;          // smooth_filter diagonal = 0
        const f4* qr = (const f4*)(q + (size_t)j * LPn);
        #pragma unroll
        for (int c = 0; c < 12; ++c) {
            f4 qv = qr[c];
            acc[c].x = fmaf(w, qv.x, acc[c].x);
            acc[c].y = fmaf(w, qv.y, acc[c].y);
            acc[c].z = fmaf(w, qv.z, acc[c].z);
            acc[c].w = fmaf(w, qv.w, acc[c].w);
        }
    }
    size_t base = (size_t)blockIdx.y * LPn * VPn + row;
    #pragma unroll
    for (int c = 0; c < 12; ++c) {
        part[base + (size_t)(4 * c + 0) * VPn] = acc[c].x;
        part[base + (size_t)(4 * c + 1) * VPn] = acc[c].y;
        part[base + (size_t)(4 * c + 2) * VPn] = acc[c].z;
        part[base + (size_t)(4 * c + 3) * VPn] = acc[c].w;
    }
}

// ---------------- general tiled body: partials = (W [*G]) @ X ----------------
template <int USEG>
__device__ __forceinline__ void mat_gen_body(const float* __restrict__ W,
                                             const float* __restrict__ X,
                                             const float* __restrict__ xyz,
                                             float* __restrict__ part, int jchunk) {
    __shared__ float ldsW[256][33];
    int t = threadIdx.x;
    int row = blockIdx.x * 256 + t;
    bool act = (row < Vn);
    int j0 = blockIdx.y * jchunk;
    int j1 = j0 + jchunk; if (j1 > Vn) j1 = Vn;
    f4 xi = make_float4(0.f, 0.f, 0.f, 0.f);
    if (USEG && act) xi = *(const f4*)(xyz + (size_t)row * 4);
    f4 acc[12];
    #pragma unroll
    for (int c = 0; c < 12; ++c) acc[c] = make_float4(0.f, 0.f, 0.f, 0.f);
    for (int jt = j0; jt < j1; jt += 32) {
        __syncthreads();
        // stage W tile: rows [bx*256, +256), cols [jt, jt+32)
        #pragma unroll
        for (int k = 0; k < 8; ++k) {
            int idx = t + k * 256;
            int r = idx >> 3;
            int cc = (idx & 7) << 2;
            int rr = blockIdx.x * 256 + r;
            int jc = jt + cc;
            float v0 = 0.f, v1 = 0.f, v2 = 0.f, v3 = 0.f;
            if (rr < Vn) {
                const float* wp = W + (size_t)rr * Vn + jc;
                if (jc + 0 < Vn) v0 = wp[0];
                if (jc + 1 < Vn) v1 = wp[1];
                if (jc + 2 < Vn) v2 = wp[2];
                if (jc + 3 < Vn) v3 = wp[3];
            }
            ldsW[r][cc + 0] = v0; ldsW[r][cc + 1] = v1;
            ldsW[r][cc + 2] = v2; ldsW[r][cc + 3] = v3;
        }
        __syncthreads();
        int jend = j1 - jt; if (jend > 32) jend = 32;
        for (int jj = 0; jj < jend; ++jj) {
            int j = jt + jj;
            float f = ldsW[t][jj];
            if (USEG) {
                f4 xj = *(const f4*)(xyz + (size_t)j * 4);
                float dx = xi.x - xj.x, dy = xi.y - xj.y, dz = xi.z - xj.z;
                float d2 = dx * dx + dy * dy + dz * dz;
                float w = __expf(-2.0f * d2);
                w = (j == row) ? 0.0f : w;
                f *= w;
            }
            const f4* qr = (const f4*)(X + (size_t)j * LPn);
            #pragma unroll
            for (int c = 0; c < 12; ++c) {
                f4 qv = qr[c];
                acc[c].x = fmaf(f, qv.x, acc[c].x);
                acc[c].y = fmaf(f, qv.y, acc[c].y);
                acc[c].z = fmaf(f, qv.z, acc[c].z);
                acc[c].w = fmaf(f, qv.w, acc[c].w);
            }
        }
    }
    if (act) {
        size_t base = (size_t)blockIdx.y * LPn * VPn + row;
        #pragma unroll
        for (int c = 0; c < 12; ++c) {
            part[base + (size_t)(4 * c + 0) * VPn] = acc[c].x;
            part[base + (size_t)(4 * c + 1) * VPn] = acc[c].y;
            part[base + (size_t)(4 * c + 2) * VPn] = acc[c].z;
            part[base + (size_t)(4 * c + 3) * VPn] = acc[c].w;
        }
    }
}

__global__ __launch_bounds__(256) void k_phi_gen(const float* __restrict__ W,
                                                 const float* __restrict__ q,
                                                 const float* __restrict__ xyz,
                                                 float* __restrict__ part,
                                                 const int* __restrict__ flags, int jchunk) {
    if (!flags[0]) return;  // F is uniform -> fast kernel owns it
    mat_gen_body<1>(W, q, xyz, part, jchunk);
}

__global__ __launch_bounds__(256) void k_sp_gen(const float* __restrict__ S,
                                                const float* __restrict__ phi,
                                                float* __restrict__ part,
                                                const int* __restrict__ flags, int jchunk) {
    if (!flags[1]) return;  // S is diagonal -> handled as row scale in k_B
    mat_gen_body<0>(S, phi, (const float*)nullptr, part, jchunk);
}

// ---------------- reduce partials -> phi_t [V][48] ----------------
__global__ __launch_bounds__(256) void k_R1(const float* __restrict__ part,
                                            float* __restrict__ phi, int NS) {
    int row = blockIdx.x * 256 + threadIdx.x;
    if (row >= Vn) return;
    #pragma unroll
    for (int c = 0; c < LPn; ++c) {
        float s = 0.f;
        for (int n = 0; n < NS; ++n) s += part[((size_t)n * LPn + c) * VPn + row];
        phi[(size_t)row * LPn + c] = s;
    }
}

// ---------------- epilogue: logits = U + scale*(pt @ C); q = softmax ----------------
__global__ __launch_bounds__(256) void k_B(const float* __restrict__ U,
                                           const float* __restrict__ phi,
                                           const float* __restrict__ part,
                                           const float* __restrict__ diagS,
                                           const float* __restrict__ Cm,
                                           const int* __restrict__ flags,
                                           float* __restrict__ qn,
                                           float* __restrict__ outp, int last, int NS) {
    __shared__ float ldsC[Ln][LPn];
    int t = threadIdx.x;
    for (int idx = t; idx < Ln * LPn; idx += 256) {
        int m = idx / LPn, l = idx - m * LPn;
        ldsC[m][l] = (l < Ln) ? Cm[(size_t)m * Ln + l] : 0.0f;
    }
    __syncthreads();
    int row = blockIdx.x * 256 + t;
    if (row >= Vn) return;
    const int sgen = flags[1];
    float pt[LPn];
    if (!sgen) {
        #pragma unroll
        for (int c = 0; c < 12; ++c) {
            f4 v = *(const f4*)(phi + (size_t)row * LPn + 4 * c);
            pt[4 * c + 0] = v.x; pt[4 * c + 1] = v.y;
            pt[4 * c + 2] = v.z; pt[4 * c + 3] = v.w;
        }
    } else {
        #pragma unroll
        for (int c = 0; c < LPn; ++c) pt[c] = 0.f;
        for (int n = 0; n < NS; ++n) {
            #pragma unroll
            for (int c = 0; c < LPn; ++c)
                pt[c] += part[((size_t)n * LPn + c) * VPn + row];
        }
    }
    float cval = ((const float*)flags)[2];
    float scale = (flags[0] ? 1.0f : cval) * (sgen ? 1.0f : diagS[row]);
    float ph[LPn];
    #pragma unroll
    for (int c = 0; c < LPn; ++c) ph[c] = 0.f;
    #pragma unroll
    for (int m = 0; m < Ln; ++m) {
        float pm = pt[m];
        #pragma unroll
        for (int c = 0; c < 12; ++c) {
            f4 cv = *(const f4*)&ldsC[m][4 * c];
            ph[4 * c + 0] = fmaf(pm, cv.x, ph[4 * c + 0]);
            ph[4 * c + 1] = fmaf(pm, cv.y, ph[4 * c + 1]);
            ph[4 * c + 2] = fmaf(pm, cv.z, ph[4 * c + 2]);
            ph[4 * c + 3] = fmaf(pm, cv.w, ph[4 * c + 3]);
        }
    }
    float lg[LPn];
    #pragma unroll
    for (int c = 0; c < 12; ++c) {
        f4 uv = *(const f4*)(U + (size_t)row * LPn + 4 * c);
        lg[4 * c + 0] = uv.x + scale * ph[4 * c + 0];
        lg[4 * c + 1] = uv.y + scale * ph[4 * c + 1];
        lg[4 * c + 2] = uv.z + scale * ph[4 * c + 2];
        lg[4 * c + 3] = uv.w + scale * ph[4 * c + 3];
    }
    float mx = lg[0];
    #pragma unroll
    for (int l = 1; l < Ln; ++l) mx = fmaxf(mx, lg[l]);
    float s = 0.f;
    float e[LPn];
    #pragma unroll
    for (int l = 0; l < Ln; ++l) { e[l] = __expf(lg[l] - mx); s += e[l]; }
    #pragma unroll
    for (int l = Ln; l < LPn; ++l) e[l] = 0.f;
    float inv = 1.0f / s;
    #pragma unroll
    for (int c = 0; c < 12; ++c) {
        f4 v = make_float4(e[4 * c + 0] * inv, e[4 * c + 1] * inv,
                           e[4 * c + 2] * inv, e[4 * c + 3] * inv);
        *(f4*)(qn + (size_t)row * LPn + 4 * c) = v;
    }
    if (last) {
        #pragma unroll
        for (int l = 0; l < Ln; ++l) outp[(size_t)row * Ln + l] = e[l] * inv;
    }
}

// ---------------- host launcher ----------------
extern "C" void kernel_launch(void* const* d_in, const int* in_sizes, int n_in,
                              void* d_out, int out_size, void* d_ws, size_t ws_size,
                              hipStream_t stream) {
    const float* didx   = (const float*)d_in[0];   // [V,42]
    const float* coords = (const float*)d_in[1];   // [V,3]
    const float* Fw     = (const float*)d_in[2];   // [V,V]
    const float* Sw     = (const float*)d_in[3];   // [V,V]
    const float* Cm     = (const float*)d_in[4];   // [42,42]
    float* outp = (float*)d_out;
    float* wsf = (float*)d_ws;

    int*   flags = (int*)wsf;                      // 16 floats reserved
    float* diagS = wsf + 16;                       // VPn
    float* xyz   = diagS + VPn;                    // VPn*4
    float* U     = xyz + (size_t)VPn * 4;          // VPn*48
    float* qA    = U + (size_t)VPn * LPn;
    float* qB    = qA + (size_t)VPn * LPn;
    float* phi   = qB + (size_t)VPn * LPn;
    float* part  = phi + (size_t)VPn * LPn;

    size_t base_f = 16 + (size_t)VPn * (1 + 4 + 4 * LPn);
    int NS = 12;
    while (NS > 1 && (base_f + (size_t)NS * LPn * VPn) * 4 > ws_size) NS--;
    int jchunk = (Vn + NS - 1) / NS;

    hipLaunchKernelGGL(k_init0, dim3(1), dim3(1), 0, stream, flags, Fw);
    hipLaunchKernelGGL(k_detect, dim3(RBn, 1024), dim3(256), 0, stream, Fw, Sw, flags, diagS);
    hipLaunchKernelGGL(k_initU, dim3(RBn), dim3(256), 0, stream, didx, coords, U, qA, xyz);

    float* qcur = qA;
    float* qnxt = qB;
    for (int it = 0; it < NITER; ++it) {
        hipLaunchKernelGGL(k_phi_fast, dim3(RBn, NS), dim3(256), 0, stream,
                           qcur, xyz, part, flags, jchunk);
        hipLaunchKernelGGL(k_phi_gen, dim3(RBn, NS), dim3(256), 0, stream,
                           Fw, qcur, xyz, part, flags, jchunk);
        hipLaunchKernelGGL(k_R1, dim3(RBn), dim3(256), 0, stream, part, phi, NS);
        hipLaunchKernelGGL(k_sp_gen, dim3(RBn, NS), dim3(256), 0, stream,
                           Sw, phi, part, flags, jchunk);
        hipLaunchKernelGGL(k_B, dim3(RBn), dim3(256), 0, stream,
                           U, phi, part, diagS, Cm, flags, qnxt, outp,
                           (it == NITER - 1) ? 1 : 0, NS);
        float* tmp = qcur; qcur = qnxt; qnxt = tmp;
    }
}

// Round 2
// 1551.457 us; speedup vs baseline: 1.5580x; 1.5580x over previous
//
#include <hip/hip_runtime.h>
#include <stdint.h>

#define Vn 10242
#define Ln 42
#define LPn 48
#define VPn 10496    /* 41*256 padded rows */
#define RBn 41
#define JPAD 10368   /* 81*128 : j range padded to tile multiple */
#define NITER 5
#define SCL 1.69864360f  /* sqrt(2*log2(e)) : exp(-2 d^2) == exp2(-sum (SCL*dx)^2) */

typedef float4 f4;

// ---------------- structure detection: F uniform? S diagonal? diag(S) ----------------
__global__ __launch_bounds__(256) void k_detect(const float* __restrict__ F,
                                                const float* __restrict__ S,
                                                int* flags, float* __restrict__ diagS) {
    int jj = blockIdx.x * 256 + threadIdx.x;          // float2 column index
    if (jj >= Vn / 2) return;
    int j = jj * 2;
    const float c0 = F[0];
    int violF = 0, violS = 0;
    for (int i = blockIdx.y; i < Vn; i += (int)gridDim.y) {
        size_t off = (size_t)i * Vn + j;
        float2 f = *(const float2*)(F + off);
        float2 s = *(const float2*)(S + off);
        violF |= (f.x != c0) | (f.y != c0);
        if (i == j)          { diagS[j] = s.x;     violS |= (s.y != 0.0f); }
        else if (i == j + 1) { diagS[j + 1] = s.y; violS |= (s.x != 0.0f); }
        else                 violS |= (s.x != 0.0f) | (s.y != 0.0f);
    }
    if (violF) atomicOr(&flags[0], 1);
    if (violS) atomicOr(&flags[1], 1);
}

// ---------------- C identity? ----------------
__global__ void k_detC(const float* __restrict__ Cm, int* flags) {
    int viol = 0;
    for (int idx = threadIdx.x; idx < Ln * Ln; idx += 256) {
        int r = idx / Ln, c = idx - r * Ln;
        float expct = (r == c) ? 1.0f : 0.0f;
        viol |= (Cm[idx] != expct);
    }
    if (viol) atomicOr(&flags[3], 1);
}

// ---------------- U = log(clip), q0 = softmax(U), scaled coords; zero pads ----------------
__global__ __launch_bounds__(256) void k_initU(const float* __restrict__ didx,
                                               const float* __restrict__ coords,
                                               float* __restrict__ U, float* __restrict__ qA,
                                               float* __restrict__ qB, float* __restrict__ xyz) {
    int row = blockIdx.x * 256 + threadIdx.x;   // covers [0, VPn)
    if (row >= Vn) {
        #pragma unroll
        for (int l = 0; l < LPn; ++l) {
            U[(size_t)row * LPn + l] = 0.0f;
            qA[(size_t)row * LPn + l] = 0.0f;
            qB[(size_t)row * LPn + l] = 0.0f;
        }
        *(f4*)(xyz + (size_t)row * 4) = make_float4(0.f, 0.f, 0.f, 0.f);
        return;
    }
    xyz[(size_t)row * 4 + 0] = SCL * coords[(size_t)row * 3 + 0];
    xyz[(size_t)row * 4 + 1] = SCL * coords[(size_t)row * 3 + 1];
    xyz[(size_t)row * 4 + 2] = SCL * coords[(size_t)row * 3 + 2];
    xyz[(size_t)row * 4 + 3] = 0.0f;
    float u[Ln];
    float mx = -3.0e38f;
    #pragma unroll
    for (int l = 0; l < Ln; ++l) {
        float x = didx[(size_t)row * Ln + l];
        x = fminf(fmaxf(x, 1e-6f), 1.0f);
        u[l] = __logf(x);
        mx = fmaxf(mx, u[l]);
    }
    float s = 0.0f;
    float e[Ln];
    #pragma unroll
    for (int l = 0; l < Ln; ++l) { e[l] = __expf(u[l] - mx); s += e[l]; }
    float inv = 1.0f / s;
    #pragma unroll
    for (int l = 0; l < Ln; ++l) {
        U[(size_t)row * LPn + l] = u[l];
        qA[(size_t)row * LPn + l] = e[l] * inv;
    }
    #pragma unroll
    for (int l = Ln; l < LPn; ++l) {
        U[(size_t)row * LPn + l] = 0.0f;
        qA[(size_t)row * LPn + l] = 0.0f;
        qB[(size_t)row * LPn + l] = 0.0f;  // keep pads of both q buffers zero
    }
}

// ---------------- shared memory union (fast q-tile | general W-tile) ----------------
union ShMem {
    float w[256][33];
    struct { float q[128][LPn]; f4 x[128]; } f;
};

// ---------------- general tiled body: partials = (W [*G]) @ X ----------------
template <int USEG>
__device__ __forceinline__ void mat_gen_body(const float* __restrict__ W,
                                             const float* __restrict__ X,
                                             const float* __restrict__ xyz,
                                             float* __restrict__ part, int jchunk,
                                             ShMem& sh) {
    int t = threadIdx.x;
    int row = blockIdx.x * 256 + t;
    bool act = (row < Vn);
    int j0 = blockIdx.y * jchunk;
    int j1 = j0 + jchunk; if (j1 > Vn) j1 = Vn;
    f4 xi = make_float4(0.f, 0.f, 0.f, 0.f);
    if (USEG && act) xi = *(const f4*)(xyz + (size_t)row * 4);
    f4 acc[12];
    #pragma unroll
    for (int c = 0; c < 12; ++c) acc[c] = make_float4(0.f, 0.f, 0.f, 0.f);
    for (int jt = j0; jt < j1; jt += 32) {
        __syncthreads();
        #pragma unroll
        for (int k = 0; k < 8; ++k) {
            int idx = t + k * 256;
            int r = idx >> 3;
            int cc = (idx & 7) << 2;
            int rr = blockIdx.x * 256 + r;
            int jc = jt + cc;
            float v0 = 0.f, v1 = 0.f, v2 = 0.f, v3 = 0.f;
            if (rr < Vn) {
                const float* wp = W + (size_t)rr * Vn + jc;
                if (jc + 0 < Vn) v0 = wp[0];
                if (jc + 1 < Vn) v1 = wp[1];
                if (jc + 2 < Vn) v2 = wp[2];
                if (jc + 3 < Vn) v3 = wp[3];
            }
            sh.w[r][cc + 0] = v0; sh.w[r][cc + 1] = v1;
            sh.w[r][cc + 2] = v2; sh.w[r][cc + 3] = v3;
        }
        __syncthreads();
        int jend = j1 - jt; if (jend > 32) jend = 32;
        for (int jj = 0; jj < jend; ++jj) {
            int j = jt + jj;
            float f = sh.w[t][jj];
            if (USEG) {
                f4 xj = *(const f4*)(xyz + (size_t)j * 4);
                float dx = xi.x - xj.x, dy = xi.y - xj.y, dz = xi.z - xj.z;
                float t2 = dx * dx; t2 = fmaf(dy, dy, t2); t2 = fmaf(dz, dz, t2);
                float w = exp2f(-t2);
                w = (j == row) ? 0.0f : w;
                f *= w;
            }
            const f4* qr = (const f4*)(X + (size_t)j * LPn);
            #pragma unroll
            for (int c = 0; c < 12; ++c) {
                f4 qv = qr[c];
                acc[c].x = fmaf(f, qv.x, acc[c].x);
                acc[c].y = fmaf(f, qv.y, acc[c].y);
                acc[c].z = fmaf(f, qv.z, acc[c].z);
                acc[c].w = fmaf(f, qv.w, acc[c].w);
            }
        }
    }
    size_t base = (size_t)blockIdx.y * LPn * VPn + row;
    if (act) {
        #pragma unroll
        for (int c = 0; c < 12; ++c) {
            part[base + (size_t)(4 * c + 0) * VPn] = acc[c].x;
            part[base + (size_t)(4 * c + 1) * VPn] = acc[c].y;
            part[base + (size_t)(4 * c + 2) * VPn] = acc[c].z;
            part[base + (size_t)(4 * c + 3) * VPn] = acc[c].w;
        }
    } else if (row < VPn) {
        #pragma unroll
        for (int c = 0; c < LPn; ++c) part[base + (size_t)c * VPn] = 0.0f;
    }
}

// ---------------- merged filter pass: fast (G uniform-F) or general ----------------
__global__ __launch_bounds__(256, 4) void k_phi(const float* __restrict__ Fw,
                                                const float* __restrict__ q,
                                                const float* __restrict__ xyz,
                                                float* __restrict__ part,
                                                const int* __restrict__ flags, int jchunk) {
    __shared__ ShMem sh;
    if (flags[0]) { mat_gen_body<1>(Fw, q, xyz, part, jchunk, sh); return; }
    int t = threadIdx.x;
    int row = blockIdx.x * 256 + t;                  // < VPn always
    f4 xi = *(const f4*)(xyz + (size_t)row * 4);
    f4 acc[12];
    #pragma unroll
    for (int c = 0; c < 12; ++c) acc[c] = make_float4(0.f, 0.f, 0.f, 0.f);
    int j0 = blockIdx.y * jchunk;
    int j1 = j0 + jchunk; if (j1 > JPAD) j1 = JPAD;
    for (int jt = j0; jt < j1; jt += 128) {
        __syncthreads();
        #pragma unroll
        for (int k = 0; k < 6; ++k) {
            int idx = t + k * 256;
            int r = idx / 12;
            int c = idx - r * 12;
            f4 v = *(const f4*)(q + (size_t)(jt + r) * LPn + (c << 2));
            *(f4*)&sh.f.q[r][c << 2] = v;
        }
        if (t < 128) sh.f.x[t] = *(const f4*)(xyz + (size_t)(jt + t) * 4);
        __syncthreads();
        #pragma unroll 2
        for (int jj = 0; jj < 128; ++jj) {
            f4 xj = sh.f.x[jj];
            float dx = xi.x - xj.x, dy = xi.y - xj.y, dz = xi.z - xj.z;
            float t2 = dx * dx; t2 = fmaf(dy, dy, t2); t2 = fmaf(dz, dz, t2);
            float w = exp2f(-t2);                    // includes j==row (w=1), fixed in k_R0
            const f4* qr = (const f4*)sh.f.q[jj];
            #pragma unroll
            for (int c = 0; c < 12; ++c) {
                f4 qv = qr[c];
                acc[c].x = fmaf(w, qv.x, acc[c].x);
                acc[c].y = fmaf(w, qv.y, acc[c].y);
                acc[c].z = fmaf(w, qv.z, acc[c].z);
                acc[c].w = fmaf(w, qv.w, acc[c].w);
            }
        }
    }
    size_t base = (size_t)blockIdx.y * LPn * VPn + row;
    #pragma unroll
    for (int c = 0; c < 12; ++c) {
        part[base + (size_t)(4 * c + 0) * VPn] = acc[c].x;
        part[base + (size_t)(4 * c + 1) * VPn] = acc[c].y;
        part[base + (size_t)(4 * c + 2) * VPn] = acc[c].z;
        part[base + (size_t)(4 * c + 3) * VPn] = acc[c].w;
    }
}

// ---------------- general spatial pass: part = S @ phi (only if S not diagonal) ----------------
__global__ __launch_bounds__(256, 4) void k_sp(const float* __restrict__ Sw,
                                               const float* __restrict__ phi,
                                               float* __restrict__ part,
                                               const int* __restrict__ flags, int jchunk) {
    if (!flags[1]) return;
    __shared__ ShMem sh;
    mat_gen_body<0>(Sw, phi, (const float*)nullptr, part, jchunk, sh);
}

// ---------------- reduce partials -> phi [row][48]; optional diagonal subtract ----------------
__global__ __launch_bounds__(256) void k_R0(const float* __restrict__ part,
                                            const float* __restrict__ q,
                                            float* __restrict__ phi,
                                            const int* __restrict__ flags,
                                            int NS, int gate) {
    if (gate && !flags[1]) return;                 // second reduce only for general S
    int tg = blockIdx.x * 256 + threadIdx.x;       // 492*256 == 48 * (VPn/4)
    int c = tg / (VPn / 4);
    int r4 = (tg - c * (VPn / 4)) * 4;
    f4 s = make_float4(0.f, 0.f, 0.f, 0.f);
    for (int n = 0; n < NS; ++n) {
        f4 v = *(const f4*)(part + ((size_t)n * LPn + c) * VPn + r4);
        s.x += v.x; s.y += v.y; s.z += v.z; s.w += v.w;
    }
    if (!gate && !flags[0]) {                      // fast filter included diagonal w=1
        s.x -= q[(size_t)(r4 + 0) * LPn + c];
        s.y -= q[(size_t)(r4 + 1) * LPn + c];
        s.z -= q[(size_t)(r4 + 2) * LPn + c];
        s.w -= q[(size_t)(r4 + 3) * LPn + c];
    }
    phi[(size_t)(r4 + 0) * LPn + c] = s.x;
    phi[(size_t)(r4 + 1) * LPn + c] = s.y;
    phi[(size_t)(r4 + 2) * LPn + c] = s.z;
    phi[(size_t)(r4 + 3) * LPn + c] = s.w;
}

// ---------------- epilogue: logits = U + scale*(pt [@C]); q = softmax ----------------
__global__ __launch_bounds__(256) void k_B(const float* __restrict__ U,
                                           const float* __restrict__ phi,
                                           const float* __restrict__ phi2,
                                           const float* __restrict__ diagS,
                                           const float* __restrict__ Cm,
                                           const float* __restrict__ Fw,
                                           const int* __restrict__ flags,
                                           float* __restrict__ qn,
                                           float* __restrict__ outp, int last) {
    __shared__ float ldsC[Ln][LPn];
    int t = threadIdx.x;
    if (flags[3]) {
        for (int idx = t; idx < Ln * LPn; idx += 256) {
            int m = idx / LPn, l = idx - m * LPn;
            ldsC[m][l] = (l < Ln) ? Cm[(size_t)m * Ln + l] : 0.0f;
        }
    }
    __syncthreads();
    int row = blockIdx.x * 256 + t;
    if (row >= Vn) return;
    const float* src = flags[1] ? phi2 : phi;
    float pt[LPn];
    #pragma unroll
    for (int c = 0; c < 12; ++c) {
        f4 v = *(const f4*)(src + (size_t)row * LPn + 4 * c);
        pt[4 * c + 0] = v.x; pt[4 * c + 1] = v.y;
        pt[4 * c + 2] = v.z; pt[4 * c + 3] = v.w;
    }
    float scale = (flags[0] ? 1.0f : Fw[0]) * (flags[1] ? 1.0f : diagS[row]);
    float ph[LPn];
    if (flags[3]) {
        #pragma unroll
        for (int c = 0; c < LPn; ++c) ph[c] = 0.f;
        #pragma unroll
        for (int m = 0; m < Ln; ++m) {
            float pm = pt[m];
            #pragma unroll
            for (int c = 0; c < 12; ++c) {
                f4 cv = *(const f4*)&ldsC[m][4 * c];
                ph[4 * c + 0] = fmaf(pm, cv.x, ph[4 * c + 0]);
                ph[4 * c + 1] = fmaf(pm, cv.y, ph[4 * c + 1]);
                ph[4 * c + 2] = fmaf(pm, cv.z, ph[4 * c + 2]);
                ph[4 * c + 3] = fmaf(pm, cv.w, ph[4 * c + 3]);
            }
        }
    } else {
        #pragma unroll
        for (int c = 0; c < LPn; ++c) ph[c] = pt[c];
    }
    float lg[LPn];
    #pragma unroll
    for (int c = 0; c < 12; ++c) {
        f4 uv = *(const f4*)(U + (size_t)row * LPn + 4 * c);
        lg[4 * c + 0] = uv.x + scale * ph[4 * c + 0];
        lg[4 * c + 1] = uv.y + scale * ph[4 * c + 1];
        lg[4 * c + 2] = uv.z + scale * ph[4 * c + 2];
        lg[4 * c + 3] = uv.w + scale * ph[4 * c + 3];
    }
    float mx = lg[0];
    #pragma unroll
    for (int l = 1; l < Ln; ++l) mx = fmaxf(mx, lg[l]);
    float s = 0.f;
    float e[LPn];
    #pragma unroll
    for (int l = 0; l < Ln; ++l) { e[l] = __expf(lg[l] - mx); s += e[l]; }
    #pragma unroll
    for (int l = Ln; l < LPn; ++l) e[l] = 0.f;
    float inv = 1.0f / s;
    #pragma unroll
    for (int c = 0; c < 12; ++c) {
        f4 v = make_float4(e[4 * c + 0] * inv, e[4 * c + 1] * inv,
                           e[4 * c + 2] * inv, e[4 * c + 3] * inv);
        *(f4*)(qn + (size_t)row * LPn + 4 * c) = v;
    }
    if (last) {
        #pragma unroll
        for (int l = 0; l < Ln; ++l) outp[(size_t)row * Ln + l] = e[l] * inv;
    }
}

// ---------------- host launcher ----------------
extern "C" void kernel_launch(void* const* d_in, const int* in_sizes, int n_in,
                              void* d_out, int out_size, void* d_ws, size_t ws_size,
                              hipStream_t stream) {
    const float* didx   = (const float*)d_in[0];
    const float* coords = (const float*)d_in[1];
    const float* Fw     = (const float*)d_in[2];
    const float* Sw     = (const float*)d_in[3];
    const float* Cm     = (const float*)d_in[4];
    float* outp = (float*)d_out;
    float* wsf = (float*)d_ws;

    int*   flags = (int*)wsf;                      // 16 floats reserved
    float* diagS = wsf + 16;                       // VPn
    float* xyz   = diagS + VPn;                    // VPn*4
    float* U     = xyz + (size_t)VPn * 4;          // VPn*48
    float* qA    = U + (size_t)VPn * LPn;
    float* qB    = qA + (size_t)VPn * LPn;
    float* phi   = qB + (size_t)VPn * LPn;
    float* phi2  = phi + (size_t)VPn * LPn;
    float* part  = phi2 + (size_t)VPn * LPn;

    size_t base_f = 16 + (size_t)VPn * (1 + 4 + 5 * LPn);
    int jchunk = 512;
    int NS = (JPAD + jchunk - 1) / jchunk;         // 21
    while (NS > 1 && (base_f + (size_t)NS * LPn * VPn) * 4 > ws_size) {
        jchunk += 128;
        NS = (JPAD + jchunk - 1) / jchunk;
    }

    hipMemsetAsync(flags, 0, 16, stream);
    hipLaunchKernelGGL(k_detect, dim3((Vn / 2 + 255) / 256, 1024), dim3(256), 0, stream,
                       Fw, Sw, flags, diagS);
    hipLaunchKernelGGL(k_detC, dim3(1), dim3(256), 0, stream, Cm, flags);
    hipLaunchKernelGGL(k_initU, dim3(RBn), dim3(256), 0, stream, didx, coords, U, qA, qB, xyz);

    float* qcur = qA;
    float* qnxt = qB;
    for (int it = 0; it < NITER; ++it) {
        hipLaunchKernelGGL(k_phi, dim3(RBn, NS), dim3(256), 0, stream,
                           Fw, qcur, xyz, part, flags, jchunk);
        hipLaunchKernelGGL(k_R0, dim3(LPn * (VPn / 4) / 256), dim3(256), 0, stream,
                           part, qcur, phi, flags, NS, 0);
        hipLaunchKernelGGL(k_sp, dim3(RBn, NS), dim3(256), 0, stream,
                           Sw, phi, part, flags, jchunk);
        hipLaunchKernelGGL(k_R0, dim3(LPn * (VPn / 4) / 256), dim3(256), 0, stream,
                           part, qcur, phi2, flags, NS, 1);
        hipLaunchKernelGGL(k_B, dim3(RBn), dim3(256), 0, stream,
                           U, phi, phi2, diagS, Cm, Fw, flags, qnxt, outp,
                           (it == NITER - 1) ? 1 : 0);
        float* tmp = qcur; qcur = qnxt; qnxt = tmp;
    }
}

// Round 4
// 653.468 us; speedup vs baseline: 3.6991x; 2.3742x over previous
//
#include <hip/hip_runtime.h>
#include <stdint.h>

#define Vn 10242
#define Ln 42
#define LPn 48
#define VPn 10496    /* 41*256 = 82*128 padded rows */
#define RBn 41
#define JPAD 10368   /* 162*64 : j range padded to K-tile multiple */
#define NITER 5
#define SCL 1.69864360f  /* sqrt(2*log2(e)) : exp(-2 d^2) == exp2(-|SCL*dx|^2) */
#define BR 128

typedef float4 f4;
typedef short bf16x8 __attribute__((ext_vector_type(8)));
typedef float f32x4 __attribute__((ext_vector_type(4)));

__device__ __forceinline__ unsigned cvtpk_bf16(float a, float b) {
    unsigned r;
    asm("v_cvt_pk_bf16_f32 %0, %1, %2" : "=v"(r) : "v"(a), "v"(b));
    return r;  // lo16 = bf16(a), hi16 = bf16(b)
}
__device__ __forceinline__ unsigned short f2bf_rne(float f) {
    unsigned u = __float_as_uint(f);
    u = (u + 0x7fffu + ((u >> 16) & 1u)) >> 16;
    return (unsigned short)u;
}
__device__ __forceinline__ float bf2f(unsigned short h) {
    return __uint_as_float(((unsigned)h) << 16);
}

// ---------------- structure detection: F uniform? S diagonal? diag(S) ----------------
__global__ __launch_bounds__(256) void k_detect(const float* __restrict__ F,
                                                const float* __restrict__ S,
                                                int* flags, float* __restrict__ diagS) {
    int jj = blockIdx.x * 256 + threadIdx.x;          // float2 column index
    if (jj >= Vn / 2) return;
    int j = jj * 2;
    const float c0 = F[0];
    int violF = 0, violS = 0;
    for (int i = blockIdx.y; i < Vn; i += (int)gridDim.y) {
        size_t off = (size_t)i * Vn + j;
        float2 f = *(const float2*)(F + off);
        float2 s = *(const float2*)(S + off);
        violF |= (f.x != c0) | (f.y != c0);
        if (i == j)          { diagS[j] = s.x;     violS |= (s.y != 0.0f); }
        else if (i == j + 1) { diagS[j + 1] = s.y; violS |= (s.x != 0.0f); }
        else                 violS |= (s.x != 0.0f) | (s.y != 0.0f);
    }
    if (violF) atomicOr(&flags[0], 1);
    if (violS) atomicOr(&flags[1], 1);
}

// ---------------- C identity? ----------------
__global__ void k_detC(const float* __restrict__ Cm, int* flags) {
    int viol = 0;
    for (int idx = threadIdx.x; idx < Ln * Ln; idx += 256) {
        int r = idx / Ln, c = idx - r * Ln;
        float expct = (r == c) ? 1.0f : 0.0f;
        viol |= (Cm[idx] != expct);
    }
    if (viol) atomicOr(&flags[3], 1);
}

// ---------------- U, q0 = softmax(U), scaled coords, qT hi/lo bf16; zero pads ----------------
__global__ __launch_bounds__(256) void k_initU(const float* __restrict__ didx,
                                               const float* __restrict__ coords,
                                               float* __restrict__ U, float* __restrict__ qA,
                                               float* __restrict__ qB,
                                               unsigned short* __restrict__ qTAh,
                                               unsigned short* __restrict__ qTAl,
                                               unsigned short* __restrict__ qTBh,
                                               unsigned short* __restrict__ qTBl,
                                               float* __restrict__ xyz) {
    int row = blockIdx.x * 256 + threadIdx.x;   // covers [0, VPn)
    if (row >= Vn) {
        #pragma unroll
        for (int l = 0; l < LPn; ++l) {
            U[(size_t)row * LPn + l] = 0.0f;
            qA[(size_t)row * LPn + l] = 0.0f;
            qB[(size_t)row * LPn + l] = 0.0f;
            qTAh[(size_t)l * VPn + row] = 0;
            qTAl[(size_t)l * VPn + row] = 0;
            qTBh[(size_t)l * VPn + row] = 0;
            qTBl[(size_t)l * VPn + row] = 0;
        }
        *(f4*)(xyz + (size_t)row * 4) = make_float4(0.f, 0.f, 0.f, 0.f);
        return;
    }
    float ux = SCL * coords[(size_t)row * 3 + 0];
    float uy = SCL * coords[(size_t)row * 3 + 1];
    float uz = SCL * coords[(size_t)row * 3 + 2];
    float ss = ux * ux + uy * uy + uz * uz;
    *(f4*)(xyz + (size_t)row * 4) = make_float4(ux, uy, uz, ss);
    float u[Ln];
    float mx = -3.0e38f;
    #pragma unroll
    for (int l = 0; l < Ln; ++l) {
        float x = didx[(size_t)row * Ln + l];
        x = fminf(fmaxf(x, 1e-6f), 1.0f);
        u[l] = __logf(x);
        mx = fmaxf(mx, u[l]);
    }
    float s = 0.0f;
    float e[Ln];
    #pragma unroll
    for (int l = 0; l < Ln; ++l) { e[l] = __expf(u[l] - mx); s += e[l]; }
    float inv = 1.0f / s;
    #pragma unroll
    for (int l = 0; l < Ln; ++l) {
        float qv = e[l] * inv;
        unsigned short h = f2bf_rne(qv);
        U[(size_t)row * LPn + l] = u[l];
        qA[(size_t)row * LPn + l] = qv;
        qTAh[(size_t)l * VPn + row] = h;
        qTAl[(size_t)l * VPn + row] = f2bf_rne(qv - bf2f(h));
    }
    #pragma unroll
    for (int l = Ln; l < LPn; ++l) {
        U[(size_t)row * LPn + l] = 0.0f;
        qA[(size_t)row * LPn + l] = 0.0f;
        qB[(size_t)row * LPn + l] = 0.0f;
        qTAh[(size_t)l * VPn + row] = 0;
        qTAl[(size_t)l * VPn + row] = 0;
        qTBh[(size_t)l * VPn + row] = 0;  // k_B never writes pad labels
        qTBl[(size_t)l * VPn + row] = 0;
    }
}

// ---------------- FAST filter pass: part = G @ q via double-bf16 MFMA (4 passes) ----------------
__global__ __launch_bounds__(256, 3) void k_phi_f(const unsigned short* __restrict__ qTh,
                                                  const unsigned short* __restrict__ qTl,
                                                  const f4* __restrict__ xyz4,
                                                  float* __restrict__ part,
                                                  const int* __restrict__ flags, int jchunk) {
    if (flags[0]) return;                          // general kernel owns this case
    __shared__ uint4 Ah[8][BR];                    // w_hi tile (16 KB)
    __shared__ uint4 Al[8][BR];                    // w_lo tile (16 KB)
    __shared__ uint4 Bh[LPn][8];                   // q_hi tile (6 KB)
    __shared__ uint4 Bl[LPn][8];                   // q_lo tile (6 KB)
    const int t = threadIdx.x;
    const int lane = t & 63;
    const int wv = t >> 6;
    const int lo16 = lane & 15, hi4 = lane >> 4;
    const int rowbase = blockIdx.x * BR;
    f4 p0 = xyz4[rowbase + lane];
    f4 p1 = xyz4[rowbase + lane + 64];
    const float v0x = 2.f * p0.x, v0y = 2.f * p0.y, v0z = 2.f * p0.z, ns0 = -p0.w;
    const float v1x = 2.f * p1.x, v1y = 2.f * p1.y, v1z = 2.f * p1.z, ns1 = -p1.w;
    f32x4 acc[2][3];
    #pragma unroll
    for (int rs = 0; rs < 2; ++rs)
        #pragma unroll
        for (int cs = 0; cs < 3; ++cs) acc[rs][cs] = (f32x4){0.f, 0.f, 0.f, 0.f};
    const int j0 = blockIdx.y * jchunk;
    int j1 = j0 + jchunk; if (j1 > JPAD) j1 = JPAD;
    const int n0 = t >> 3, sl0 = t & 7;
    const int s1 = t + 256;
    const int n1 = s1 >> 3, sl1 = s1 & 7;
    const bool has1 = (s1 < LPn * 8);
    for (int jt = j0; jt < j1; jt += 64) {
        // --- B-tile prefetch into regs (latency hides under w-gen) ---
        uint4 bh0 = *(const uint4*)(qTh + (size_t)n0 * VPn + jt + sl0 * 8);
        uint4 bl0 = *(const uint4*)(qTl + (size_t)n0 * VPn + jt + sl0 * 8);
        uint4 bh1, bl1;
        if (has1) {
            bh1 = *(const uint4*)(qTh + (size_t)n1 * VPn + jt + sl1 * 8);
            bl1 = *(const uint4*)(qTl + (size_t)n1 * VPn + jt + sl1 * 8);
        }
        // --- w-gen: wave wv computes j in [jt+wv*16, +16) for rows lane, lane+64 ---
        const int jb = __builtin_amdgcn_readfirstlane(jt + wv * 16);
        unsigned ph0[8], ph1[8], pl0[8], pl1[8];
        #pragma unroll
        for (int m = 0; m < 16; m += 2) {
            f4 qa = xyz4[jb + m];       // wave-uniform
            f4 qb = xyz4[jb + m + 1];
            float wa0 = exp2f(fmaf(v0z, qa.z, fmaf(v0y, qa.y, fmaf(v0x, qa.x, ns0 - qa.w))));
            float wb0 = exp2f(fmaf(v0z, qb.z, fmaf(v0y, qb.y, fmaf(v0x, qb.x, ns0 - qb.w))));
            float wa1 = exp2f(fmaf(v1z, qa.z, fmaf(v1y, qa.y, fmaf(v1x, qa.x, ns1 - qa.w))));
            float wb1 = exp2f(fmaf(v1z, qb.z, fmaf(v1y, qb.y, fmaf(v1x, qb.x, ns1 - qb.w))));
            unsigned h0 = cvtpk_bf16(wa0, wb0);
            unsigned h1 = cvtpk_bf16(wa1, wb1);
            ph0[m >> 1] = h0;
            ph1[m >> 1] = h1;
            pl0[m >> 1] = cvtpk_bf16(wa0 - __uint_as_float(h0 << 16),
                                     wb0 - __uint_as_float(h0 & 0xffff0000u));
            pl1[m >> 1] = cvtpk_bf16(wa1 - __uint_as_float(h1 << 16),
                                     wb1 - __uint_as_float(h1 & 0xffff0000u));
        }
        __syncthreads();   // previous tile's LDS reads done
        Ah[2 * wv][lane]          = make_uint4(ph0[0], ph0[1], ph0[2], ph0[3]);
        Ah[2 * wv + 1][lane]      = make_uint4(ph0[4], ph0[5], ph0[6], ph0[7]);
        Ah[2 * wv][lane + 64]     = make_uint4(ph1[0], ph1[1], ph1[2], ph1[3]);
        Ah[2 * wv + 1][lane + 64] = make_uint4(ph1[4], ph1[5], ph1[6], ph1[7]);
        Al[2 * wv][lane]          = make_uint4(pl0[0], pl0[1], pl0[2], pl0[3]);
        Al[2 * wv + 1][lane]      = make_uint4(pl0[4], pl0[5], pl0[6], pl0[7]);
        Al[2 * wv][lane + 64]     = make_uint4(pl1[0], pl1[1], pl1[2], pl1[3]);
        Al[2 * wv + 1][lane + 64] = make_uint4(pl1[4], pl1[5], pl1[6], pl1[7]);
        Bh[n0][sl0 ^ (n0 & 7)] = bh0;
        Bl[n0][sl0 ^ (n0 & 7)] = bl0;
        if (has1) {
            Bh[n1][sl1 ^ (n1 & 7)] = bh1;
            Bl[n1][sl1 ^ (n1 & 7)] = bl1;
        }
        __syncthreads();   // tiles ready
        #pragma unroll
        for (int kk = 0; kk < 2; ++kk) {
            bf16x8 a0h = *(bf16x8*)&Ah[kk * 4 + hi4][wv * 32 + lo16];
            bf16x8 a1h = *(bf16x8*)&Ah[kk * 4 + hi4][wv * 32 + 16 + lo16];
            bf16x8 a0l = *(bf16x8*)&Al[kk * 4 + hi4][wv * 32 + lo16];
            bf16x8 a1l = *(bf16x8*)&Al[kk * 4 + hi4][wv * 32 + 16 + lo16];
            #pragma unroll
            for (int cs = 0; cs < 3; ++cs) {
                int n = cs * 16 + lo16;
                int slot = (kk * 4 + hi4) ^ (n & 7);
                bf16x8 bh = *(bf16x8*)&Bh[n][slot];
                bf16x8 bl = *(bf16x8*)&Bl[n][slot];
                acc[0][cs] = __builtin_amdgcn_mfma_f32_16x16x32_bf16(a0h, bh, acc[0][cs], 0, 0, 0);
                acc[0][cs] = __builtin_amdgcn_mfma_f32_16x16x32_bf16(a0h, bl, acc[0][cs], 0, 0, 0);
                acc[0][cs] = __builtin_amdgcn_mfma_f32_16x16x32_bf16(a0l, bh, acc[0][cs], 0, 0, 0);
                acc[0][cs] = __builtin_amdgcn_mfma_f32_16x16x32_bf16(a0l, bl, acc[0][cs], 0, 0, 0);
                acc[1][cs] = __builtin_amdgcn_mfma_f32_16x16x32_bf16(a1h, bh, acc[1][cs], 0, 0, 0);
                acc[1][cs] = __builtin_amdgcn_mfma_f32_16x16x32_bf16(a1h, bl, acc[1][cs], 0, 0, 0);
                acc[1][cs] = __builtin_amdgcn_mfma_f32_16x16x32_bf16(a1l, bh, acc[1][cs], 0, 0, 0);
                acc[1][cs] = __builtin_amdgcn_mfma_f32_16x16x32_bf16(a1l, bl, acc[1][cs], 0, 0, 0);
            }
        }
    }
    size_t pb = (size_t)blockIdx.y * LPn * VPn;
    #pragma unroll
    for (int rs = 0; rs < 2; ++rs)
        #pragma unroll
        for (int cs = 0; cs < 3; ++cs) {
            int col = cs * 16 + lo16;
            int row = rowbase + wv * 32 + rs * 16 + hi4 * 4;
            *(f4*)(part + pb + (size_t)col * VPn + row) =
                make_float4(acc[rs][cs][0], acc[rs][cs][1], acc[rs][cs][2], acc[rs][cs][3]);
        }
}

// ---------------- general tiled body: partials = (W [*G]) @ X ----------------
template <int USEG>
__device__ __forceinline__ void mat_gen_body(const float* __restrict__ W,
                                             const float* __restrict__ X,
                                             const float* __restrict__ xyz,
                                             float* __restrict__ part, int jchunk) {
    __shared__ float ldsW[256][33];
    int t = threadIdx.x;
    int row = blockIdx.x * 256 + t;
    bool act = (row < Vn);
    int j0 = blockIdx.y * jchunk;
    int j1 = j0 + jchunk; if (j1 > Vn) j1 = Vn;
    f4 xi = make_float4(0.f, 0.f, 0.f, 0.f);
    if (USEG && act) xi = *(const f4*)(xyz + (size_t)row * 4);
    f4 acc[12];
    #pragma unroll
    for (int c = 0; c < 12; ++c) acc[c] = make_float4(0.f, 0.f, 0.f, 0.f);
    for (int jt = j0; jt < j1; jt += 32) {
        __syncthreads();
        #pragma unroll
        for (int k = 0; k < 8; ++k) {
            int idx = t + k * 256;
            int r = idx >> 3;
            int cc = (idx & 7) << 2;
            int rr = blockIdx.x * 256 + r;
            int jc = jt + cc;
            float v0 = 0.f, v1 = 0.f, v2 = 0.f, v3 = 0.f;
            if (rr < Vn) {
                const float* wp = W + (size_t)rr * Vn + jc;
                if (jc + 0 < Vn) v0 = wp[0];
                if (jc + 1 < Vn) v1 = wp[1];
                if (jc + 2 < Vn) v2 = wp[2];
                if (jc + 3 < Vn) v3 = wp[3];
            }
            ldsW[r][cc + 0] = v0; ldsW[r][cc + 1] = v1;
            ldsW[r][cc + 2] = v2; ldsW[r][cc + 3] = v3;
        }
        __syncthreads();
        int jend = j1 - jt; if (jend > 32) jend = 32;
        for (int jj = 0; jj < jend; ++jj) {
            int j = jt + jj;
            float f = ldsW[t][jj];
            if (USEG) {
                f4 xj = *(const f4*)(xyz + (size_t)j * 4);
                float dx = xi.x - xj.x, dy = xi.y - xj.y, dz = xi.z - xj.z;
                float t2 = dx * dx; t2 = fmaf(dy, dy, t2); t2 = fmaf(dz, dz, t2);
                float w = exp2f(-t2);
                w = (j == row) ? 0.0f : w;
                f *= w;
            }
            const f4* qr = (const f4*)(X + (size_t)j * LPn);
            #pragma unroll
            for (int c = 0; c < 12; ++c) {
                f4 qv = qr[c];
                acc[c].x = fmaf(f, qv.x, acc[c].x);
                acc[c].y = fmaf(f, qv.y, acc[c].y);
                acc[c].z = fmaf(f, qv.z, acc[c].z);
                acc[c].w = fmaf(f, qv.w, acc[c].w);
            }
        }
    }
    size_t base = (size_t)blockIdx.y * LPn * VPn + row;
    if (act) {
        #pragma unroll
        for (int c = 0; c < 12; ++c) {
            part[base + (size_t)(4 * c + 0) * VPn] = acc[c].x;
            part[base + (size_t)(4 * c + 1) * VPn] = acc[c].y;
            part[base + (size_t)(4 * c + 2) * VPn] = acc[c].z;
            part[base + (size_t)(4 * c + 3) * VPn] = acc[c].w;
        }
    } else if (row < VPn) {
        #pragma unroll
        for (int c = 0; c < LPn; ++c) part[base + (size_t)c * VPn] = 0.0f;
    }
}

__global__ __launch_bounds__(256) void k_phi_g(const float* __restrict__ W,
                                               const float* __restrict__ q,
                                               const float* __restrict__ xyz,
                                               float* __restrict__ part,
                                               const int* __restrict__ flags, int jchunk) {
    if (!flags[0]) return;
    mat_gen_body<1>(W, q, xyz, part, jchunk);
}

__global__ __launch_bounds__(256) void k_sp(const float* __restrict__ Sw,
                                            const float* __restrict__ phi,
                                            float* __restrict__ part,
                                            const int* __restrict__ flags, int jchunk) {
    if (!flags[1]) return;
    mat_gen_body<0>(Sw, phi, (const float*)nullptr, part, jchunk);
}

// ---------------- reduce partials -> phi [row][48]; bf16-exact diagonal subtract ----------------
__global__ __launch_bounds__(256) void k_R0(const float* __restrict__ part,
                                            const unsigned short* __restrict__ qTh,
                                            const unsigned short* __restrict__ qTl,
                                            float* __restrict__ phi,
                                            const int* __restrict__ flags,
                                            int NS, int gate) {
    if (gate && !flags[1]) return;
    int tg = blockIdx.x * 256 + threadIdx.x;       // 492*256 == 48 * (VPn/4)
    int c = tg / (VPn / 4);
    int r4 = (tg - c * (VPn / 4)) * 4;
    f4 s = make_float4(0.f, 0.f, 0.f, 0.f);
    for (int n = 0; n < NS; ++n) {
        f4 v = *(const f4*)(part + ((size_t)n * LPn + c) * VPn + r4);
        s.x += v.x; s.y += v.y; s.z += v.z; s.w += v.w;
    }
    if (!gate && !flags[0]) {                      // MFMA path included diagonal w=1
        ushort4 h = *(const ushort4*)(qTh + (size_t)c * VPn + r4);
        ushort4 l = *(const ushort4*)(qTl + (size_t)c * VPn + r4);
        s.x -= bf2f(h.x) + bf2f(l.x);
        s.y -= bf2f(h.y) + bf2f(l.y);
        s.z -= bf2f(h.z) + bf2f(l.z);
        s.w -= bf2f(h.w) + bf2f(l.w);
    }
    phi[(size_t)(r4 + 0) * LPn + c] = s.x;
    phi[(size_t)(r4 + 1) * LPn + c] = s.y;
    phi[(size_t)(r4 + 2) * LPn + c] = s.z;
    phi[(size_t)(r4 + 3) * LPn + c] = s.w;
}

// ---------------- epilogue: logits = U + scale*(pt [@C]); q = softmax; emit q + qT hi/lo ----------------
__global__ __launch_bounds__(256) void k_B(const float* __restrict__ U,
                                           const float* __restrict__ phi,
                                           const float* __restrict__ phi2,
                                           const float* __restrict__ diagS,
                                           const float* __restrict__ Cm,
                                           const float* __restrict__ Fw,
                                           const int* __restrict__ flags,
                                           float* __restrict__ qn,
                                           unsigned short* __restrict__ qTnh,
                                           unsigned short* __restrict__ qTnl,
                                           float* __restrict__ outp, int last) {
    __shared__ float ldsC[Ln][LPn];
    int t = threadIdx.x;
    if (flags[3]) {
        for (int idx = t; idx < Ln * LPn; idx += 256) {
            int m = idx / LPn, l = idx - m * LPn;
            ldsC[m][l] = (l < Ln) ? Cm[(size_t)m * Ln + l] : 0.0f;
        }
    }
    __syncthreads();
    int row = blockIdx.x * 256 + t;
    if (row >= Vn) return;
    const float* src = flags[1] ? phi2 : phi;
    float pt[LPn];
    #pragma unroll
    for (int c = 0; c < 12; ++c) {
        f4 v = *(const f4*)(src + (size_t)row * LPn + 4 * c);
        pt[4 * c + 0] = v.x; pt[4 * c + 1] = v.y;
        pt[4 * c + 2] = v.z; pt[4 * c + 3] = v.w;
    }
    float scale = (flags[0] ? 1.0f : Fw[0]) * (flags[1] ? 1.0f : diagS[row]);
    float ph[LPn];
    if (flags[3]) {
        #pragma unroll
        for (int c = 0; c < LPn; ++c) ph[c] = 0.f;
        #pragma unroll
        for (int m = 0; m < Ln; ++m) {
            float pm = pt[m];
            #pragma unroll
            for (int c = 0; c < 12; ++c) {
                f4 cv = *(const f4*)&ldsC[m][4 * c];
                ph[4 * c + 0] = fmaf(pm, cv.x, ph[4 * c + 0]);
                ph[4 * c + 1] = fmaf(pm, cv.y, ph[4 * c + 1]);
                ph[4 * c + 2] = fmaf(pm, cv.z, ph[4 * c + 2]);
                ph[4 * c + 3] = fmaf(pm, cv.w, ph[4 * c + 3]);
            }
        }
    } else {
        #pragma unroll
        for (int c = 0; c < LPn; ++c) ph[c] = pt[c];
    }
    float lg[LPn];
    #pragma unroll
    for (int c = 0; c < 12; ++c) {
        f4 uv = *(const f4*)(U + (size_t)row * LPn + 4 * c);
        lg[4 * c + 0] = uv.x + scale * ph[4 * c + 0];
        lg[4 * c + 1] = uv.y + scale * ph[4 * c + 1];
        lg[4 * c + 2] = uv.z + scale * ph[4 * c + 2];
        lg[4 * c + 3] = uv.w + scale * ph[4 * c + 3];
    }
    float mx = lg[0];
    #pragma unroll
    for (int l = 1; l < Ln; ++l) mx = fmaxf(mx, lg[l]);
    float s = 0.f;
    float e[LPn];
    #pragma unroll
    for (int l = 0; l < Ln; ++l) { e[l] = __expf(lg[l] - mx); s += e[l]; }
    #pragma unroll
    for (int l = Ln; l < LPn; ++l) e[l] = 0.f;
    float inv = 1.0f / s;
    #pragma unroll
    for (int c = 0; c < 12; ++c) {
        f4 v = make_float4(e[4 * c + 0] * inv, e[4 * c + 1] * inv,
                           e[4 * c + 2] * inv, e[4 * c + 3] * inv);
        *(f4*)(qn + (size_t)row * LPn + 4 * c) = v;
    }
    #pragma unroll
    for (int l = 0; l < Ln; ++l) {
        float qv = e[l] * inv;
        unsigned short h = f2bf_rne(qv);
        qTnh[(size_t)l * VPn + row] = h;
        qTnl[(size_t)l * VPn + row] = f2bf_rne(qv - bf2f(h));
    }
    if (last) {
        #pragma unroll
        for (int l = 0; l < Ln; ++l) outp[(size_t)row * Ln + l] = e[l] * inv;
    }
}

// ---------------- host launcher ----------------
extern "C" void kernel_launch(void* const* d_in, const int* in_sizes, int n_in,
                              void* d_out, int out_size, void* d_ws, size_t ws_size,
                              hipStream_t stream) {
    const float* didx   = (const float*)d_in[0];
    const float* coords = (const float*)d_in[1];
    const float* Fw     = (const float*)d_in[2];
    const float* Sw     = (const float*)d_in[3];
    const float* Cm     = (const float*)d_in[4];
    float* outp = (float*)d_out;
    float* wsf = (float*)d_ws;

    int*   flags = (int*)wsf;                           // 16 floats reserved
    float* diagS = wsf + 16;                            // VPn
    float* xyz   = diagS + VPn;                         // VPn*4
    float* U     = xyz + (size_t)VPn * 4;               // VPn*48
    float* qA    = U + (size_t)VPn * LPn;
    float* qB    = qA + (size_t)VPn * LPn;
    float* phi   = qB + (size_t)VPn * LPn;
    float* phi2  = phi + (size_t)VPn * LPn;
    unsigned short* qTAh = (unsigned short*)(phi2 + (size_t)VPn * LPn);
    unsigned short* qTAl = qTAh + (size_t)LPn * VPn;
    unsigned short* qTBh = qTAl + (size_t)LPn * VPn;
    unsigned short* qTBl = qTBh + (size_t)LPn * VPn;
    float* part  = (float*)(qTBl + (size_t)LPn * VPn);  // NS*48*VPn

    // floats used before part: 16 + VPn*(1+4) + 5*48*VPn + 4*(48*VPn/2)
    size_t base_f = 16 + (size_t)VPn * (1 + 4) + (size_t)VPn * LPn * 5 + (size_t)VPn * LPn * 2;
    int NS = 8;
    while (NS > 1 && (base_f + (size_t)NS * LPn * VPn) * 4 > ws_size) NS >>= 1;
    int jchunkF = ((JPAD / 64 + NS - 1) / NS) * 64;
    int jchunkG = (((Vn + NS - 1) / NS) + 31) & ~31;

    hipMemsetAsync(flags, 0, 16, stream);
    hipLaunchKernelGGL(k_detect, dim3((Vn / 2 + 255) / 256, 1024), dim3(256), 0, stream,
                       Fw, Sw, flags, diagS);
    hipLaunchKernelGGL(k_detC, dim3(1), dim3(256), 0, stream, Cm, flags);
    hipLaunchKernelGGL(k_initU, dim3(RBn), dim3(256), 0, stream,
                       didx, coords, U, qA, qB, qTAh, qTAl, qTBh, qTBl, xyz);

    float* qcur = qA;  float* qnxt = qB;
    unsigned short* qThc = qTAh;  unsigned short* qTlc = qTAl;
    unsigned short* qThn = qTBh;  unsigned short* qTln = qTBl;
    for (int it = 0; it < NITER; ++it) {
        hipLaunchKernelGGL(k_phi_f, dim3(VPn / BR, NS), dim3(256), 0, stream,
                           qThc, qTlc, (const f4*)xyz, part, flags, jchunkF);
        hipLaunchKernelGGL(k_phi_g, dim3(RBn, NS), dim3(256), 0, stream,
                           Fw, qcur, xyz, part, flags, jchunkG);
        hipLaunchKernelGGL(k_R0, dim3(LPn * (VPn / 4) / 256), dim3(256), 0, stream,
                           part, qThc, qTlc, phi, flags, NS, 0);
        hipLaunchKernelGGL(k_sp, dim3(RBn, NS), dim3(256), 0, stream,
                           Sw, phi, part, flags, jchunkG);
        hipLaunchKernelGGL(k_R0, dim3(LPn * (VPn / 4) / 256), dim3(256), 0, stream,
                           part, qThc, qTlc, phi2, flags, NS, 1);
        hipLaunchKernelGGL(k_B, dim3(RBn), dim3(256), 0, stream,
                           U, phi, phi2, diagS, Cm, Fw, flags, qnxt, qThn, qTln, outp,
                           (it == NITER - 1) ? 1 : 0);
        float* tq = qcur; qcur = qnxt; qnxt = tq;
        unsigned short* th = qThc; qThc = qThn; qThn = th;
        unsigned short* tl = qTlc; qTlc = qTln; qTln = tl;
    }
}